// Round 3
// baseline (232.408 us; speedup 1.0000x reference)
//
#include <hip/hip_runtime.h>
#include <hip/hip_bf16.h>

// SkeletonLinear: out[b, 32d+n] = sum_k x[b,k] * W[32d+n, k] + bias[32d+n],
// k over [32(d-1), 32(d+1)) for node d>=1, [0,32) for d=0 (block-bidiagonal
// mask: self-loop + parent->child chain; mask==1 inside those blocks).
//
// fp32 buffers; bf16 MFMA compute (threshold is bf16-level), fp32 accumulate.
// R2 design: NO LDS, NO barriers. One wave = 16-row strip x 6 nodes.
// A-fragments loaded straight from global (lane l16 reads 32B of row l16;
// quad pairs fully consume each 64B line via L1). 8192 independent waves,
// 16 waves/CU resident -> latency-bound stall from R1 removed.

typedef __bf16 bf16x8 __attribute__((ext_vector_type(8)));
typedef float  f32x4  __attribute__((ext_vector_type(4)));

#define DIM 768          // 24 nodes * 32 ch

__device__ __forceinline__ bf16x8 cvt8(const float* __restrict__ p) {
    float4 lo = *(const float4*)p;
    float4 hi = *(const float4*)(p + 4);
    bf16x8 r;
    r[0] = (__bf16)lo.x; r[1] = (__bf16)lo.y; r[2] = (__bf16)lo.z; r[3] = (__bf16)lo.w;
    r[4] = (__bf16)hi.x; r[5] = (__bf16)hi.y; r[6] = (__bf16)hi.z; r[7] = (__bf16)hi.w;
    return r;
}

__global__ __launch_bounds__(256, 4)
void skeleton_linear_kernel(const float* __restrict__ x,
                            const float* __restrict__ w,
                            const float* __restrict__ bias,
                            float* __restrict__ out)
{
    const int tid  = threadIdx.x;
    const int lane = tid & 63;
    const int wave = tid >> 6;      // 4 waves: nodes 6w .. 6w+5
    const int quad = lane >> 4;     // A k-offset group / C row group
    const int l16  = lane & 15;     // A row within strip / B,C column

    const long row0 = (long)blockIdx.x * 16;           // 16-row strip
    const float* xrow = x + (row0 + l16) * DIM;        // A[m=l16][k]

#pragma unroll
    for (int i = 0; i < 6; ++i) {
        const int d  = wave * 6 + i;      // node id (wave-uniform)
        const int kb = 32 * d - 32;       // kt=0 -> parent cols, kt=1 -> self cols

        f32x4 acc0 = {0.f, 0.f, 0.f, 0.f};
        f32x4 acc1 = {0.f, 0.f, 0.f, 0.f};

#pragma unroll
        for (int kt = 0; kt < 2; ++kt) {
            if (d == 0 && kt == 0) continue;           // node 0: self-loop only
            const int k0 = kb + 32 * kt + 8 * quad;
            // A frag (verified layout): A[m=l16][k = k0..k0+7]
            bf16x8 a = cvt8(xrow + k0);
            // B frag: B[k][n] = W[32d + n][k]; W rows contiguous, L2-resident
            const float* w0 = w + (long)(32 * d + l16) * DIM + k0;
            acc0 = __builtin_amdgcn_mfma_f32_16x16x32_bf16(a, cvt8(w0), acc0, 0, 0, 0);
            acc1 = __builtin_amdgcn_mfma_f32_16x16x32_bf16(a, cvt8(w0 + 16 * DIM), acc1, 0, 0, 0);
        }

        // Epilogue (verified C/D layout): col = l16, row = 4*quad + reg.
        const float bi0 = bias[32 * d + l16];
        const float bi1 = bias[32 * d + 16 + l16];
        float* o = out + (row0 + 4 * quad) * DIM + 32 * d + l16;
#pragma unroll
        for (int r = 0; r < 4; ++r) {
            o[(long)r * DIM]      = acc0[r] + bi0;
            o[(long)r * DIM + 16] = acc1[r] + bi1;
        }
    }
}

extern "C" void kernel_launch(void* const* d_in, const int* in_sizes, int n_in,
                              void* d_out, int out_size, void* d_ws, size_t ws_size,
                              hipStream_t stream) {
    const float* x    = (const float*)d_in[0];   // [32768, 768] fp32
    const float* w    = (const float*)d_in[1];   // [768, 768] fp32
    const float* bias = (const float*)d_in[2];   // [768] fp32
    // d_in[3] = mask: structure hard-coded (mask==1 inside used blocks).
    float* out = (float*)d_out;                  // [32768, 768] fp32

    const int BATCH = 32768;
    dim3 grid(BATCH / 16);   // 2048 blocks x 256 threads; wave = (strip, node-sextet)
    skeleton_linear_kernel<<<grid, 256, 0, stream>>>(x, w, bias, out);
}

// Round 4
// 187.658 us; speedup vs baseline: 1.2385x; 1.2385x over previous
//
#include <hip/hip_runtime.h>
#include <hip/hip_bf16.h>

// SkeletonLinear: out[b, 32d+n] = sum_k x[b,k] * W[32d+n, k] + bias[32d+n],
// k over [32(d-1), 32(d+1)) for node d>=1, [0,32) for d=0 (block-bidiagonal
// mask: self-loop + parent->child chain; mask==1 inside those blocks).
//
// R3 design: kill scattered VMEM (R2's bind was transaction rate, not bytes).
//  - Prepack kernel: W -> bf16 B-fragments in d_ws, fragment-ordered, with
//    node0/parent fragment zero-filled (uniform main loop, no branch).
//  - Main kernel: 512 thr / 16-row strip. One 48 KB LDS buffer, two lives:
//    (a) coalesced fp32 x stage (stride 770: phase-2 reads <=4-way b128,
//        phase-3 writes 2-way = free), (b) out tile for coalesced stores.
//  - Every global access is a coalesced dwordx4 or L1-hot broadcast.

typedef __bf16 bf16x8 __attribute__((ext_vector_type(8)));
typedef float  f32x4  __attribute__((ext_vector_type(4)));

#define DIM 768
#define STRIDE 770          // fp32 elems per LDS row: 770%32=2 -> skewed banks
#define NFRAG (24 * 2 * 2)  // node x kt x ni fragments, 64 lanes x 16 B each

__device__ __forceinline__ bf16x8 cvt8(const float* __restrict__ p) {
    float4 lo = *(const float4*)p;
    float4 hi = *(const float4*)(p + 4);
    bf16x8 r;
    r[0] = (__bf16)lo.x; r[1] = (__bf16)lo.y; r[2] = (__bf16)lo.z; r[3] = (__bf16)lo.w;
    r[4] = (__bf16)hi.x; r[5] = (__bf16)hi.y; r[6] = (__bf16)hi.z; r[7] = (__bf16)hi.w;
    return r;
}

// ---- Prepack: W (fp32, masked-by-structure) -> bf16 B-fragments in ws.
// frag id fid = ((d*2+kt)*2+ni)*64 + lane; lane holds B[k=8*quad+j][n=l16]
// = W[32d+16ni+l16][32(d-1)+32kt+8*quad+j].  d==0,kt==0 -> zeros.
__global__ void prepack_w_kernel(const float* __restrict__ w, bf16x8* __restrict__ ws)
{
    const int fid = blockIdx.x * 256 + threadIdx.x;   // 0..6143
    const int lane = fid & 63;
    const int ni   = (fid >> 6) & 1;
    const int kt   = (fid >> 7) & 1;
    const int d    = fid >> 8;
    const int quad = lane >> 4, l16 = lane & 15;

    bf16x8 v;
    if (d == 0 && kt == 0) {
#pragma unroll
        for (int j = 0; j < 8; ++j) v[j] = (__bf16)0.f;
    } else {
        const float* src = w + (long)(32 * d + 16 * ni + l16) * DIM
                             + (32 * d - 32 + 32 * kt + 8 * quad);
        v = cvt8(src);
    }
    ws[fid] = v;
}

__global__ __launch_bounds__(512, 4)
void skeleton_linear_kernel(const float* __restrict__ x,
                            const float* __restrict__ bias,
                            const bf16x8* __restrict__ wfrag,
                            float* __restrict__ out)
{
    __shared__ float lds[16 * STRIDE];   // 49280 B -> 3 blocks/CU (24 waves)

    const int tid  = threadIdx.x;
    const int lane = tid & 63;
    const int wave = tid >> 6;          // 8 waves, 3 nodes each
    const int quad = lane >> 4;
    const int l16  = lane & 15;
    const long row0 = (long)blockIdx.x * 16;

    // ---- Phase 1: coalesced x stage (16 x 768 fp32 = 48 KB contiguous).
    {
        const float4* gx = (const float4*)(x + row0 * DIM);
        float4 st[6];
#pragma unroll
        for (int i = 0; i < 6; ++i) st[i] = gx[tid + 512 * i];
#pragma unroll
        for (int i = 0; i < 6; ++i) {
            int f = tid + 512 * i;
            int r = f / 192, c4 = f % 192;     // 192 float4 per row
            *(float4*)&lds[r * STRIDE + 4 * c4] = st[i];
        }
    }
    __syncthreads();

    // ---- Phase 2: MFMA. A from LDS (verified: A[m=l16][k=8*quad+j]),
    // B from prepacked ws fragments (coalesced dwordx4, L1/L2-hot).
    f32x4 acc[3][2];
#pragma unroll
    for (int i = 0; i < 3; ++i) {
        const int d = wave * 3 + i;
        f32x4 a0 = {0.f, 0.f, 0.f, 0.f};
        f32x4 a1 = {0.f, 0.f, 0.f, 0.f};
#pragma unroll
        for (int kt = 0; kt < 2; ++kt) {
            int k0 = 32 * d - 32 + 32 * kt + 8 * quad;
            int kA = k0 < 0 ? 0 : k0;          // node0/kt0: B==0, A ignored
            bf16x8 a = cvt8(&lds[l16 * STRIDE + kA]);
            const int fb = (d * 2 + kt) * 2;
            a0 = __builtin_amdgcn_mfma_f32_16x16x32_bf16(a, wfrag[fb * 64 + lane], a0, 0, 0, 0);
            a1 = __builtin_amdgcn_mfma_f32_16x16x32_bf16(a, wfrag[(fb + 1) * 64 + lane], a1, 0, 0, 0);
        }
        acc[i][0] = a0;
        acc[i][1] = a1;
    }
    __syncthreads();   // all A-reads done before LDS is overwritten

    // ---- Phase 3: C + bias -> LDS (verified C/D: col=l16, row=4*quad+reg).
    // bank = (8q + l16 + 2r + 16ni) % 32 -> exactly 2-way = free.
#pragma unroll
    for (int i = 0; i < 3; ++i) {
        const int d = wave * 3 + i;
#pragma unroll
        for (int ni = 0; ni < 2; ++ni) {
            const float bi = bias[32 * d + 16 * ni + l16];
#pragma unroll
            for (int r = 0; r < 4; ++r)
                lds[(4 * quad + r) * STRIDE + 32 * d + 16 * ni + l16] = acc[i][ni][r] + bi;
        }
    }
    __syncthreads();

    // ---- Phase 4: coalesced float4 stores.
    {
        float* go = out + row0 * DIM;
#pragma unroll
        for (int i = 0; i < 6; ++i) {
            int f = tid + 512 * i;
            int r = f / 192, c4 = f % 192;
            float4 v = *(const float4*)&lds[r * STRIDE + 4 * c4];
            *(float4*)(go + (long)r * DIM + 4 * c4) = v;
        }
    }
}

extern "C" void kernel_launch(void* const* d_in, const int* in_sizes, int n_in,
                              void* d_out, int out_size, void* d_ws, size_t ws_size,
                              hipStream_t stream) {
    const float* x    = (const float*)d_in[0];   // [32768, 768] fp32
    const float* w    = (const float*)d_in[1];   // [768, 768] fp32
    const float* bias = (const float*)d_in[2];   // [768] fp32
    // d_in[3] = mask: structure hard-coded (mask==1 inside used blocks).
    float* out = (float*)d_out;                  // [32768, 768] fp32

    bf16x8* wpack = (bf16x8*)d_ws;               // NFRAG*64*16 B = 96 KB

    prepack_w_kernel<<<NFRAG * 64 / 256, 256, 0, stream>>>(w, wpack);

    const int BATCH = 32768;
    dim3 grid(BATCH / 16);                       // 2048 blocks x 512 threads
    skeleton_linear_kernel<<<grid, 512, 0, stream>>>(x, bias, wpack, out);
}